// Round 6
// baseline (772.869 us; speedup 1.0000x reference)
//
#include <hip/hip_runtime.h>
#include <hip/hip_bf16.h>
#include <stdint.h>
#include <stddef.h>

typedef __bf16 bf16;
typedef __bf16 bf16x8 __attribute__((ext_vector_type(8)));
typedef float f32x4 __attribute__((ext_vector_type(4)));
typedef float f32x16 __attribute__((ext_vector_type(16)));
typedef __attribute__((address_space(1))) void gvoid;
typedef __attribute__((address_space(3))) void lvoid;

#define FENCE() asm volatile("" ::: "memory")
#define VMCNT(n) asm volatile("s_waitcnt vmcnt(" #n ")" ::: "memory")
#define BARS() do { FENCE(); __builtin_amdgcn_s_barrier(); FENCE(); } while (0)

// ---------------- fp32 -> bf16 elementwise convert, 8 elem/thread ----------------
__global__ __launch_bounds__(256)
void cvt_f32_bf16(const float* __restrict__ in, bf16* __restrict__ out, int n8)
{
    int i = blockIdx.x * 256 + threadIdx.x;
    if (i >= n8) return;
    const f32x4* p = (const f32x4*)in + (size_t)i * 2;
    f32x4 a = p[0], b = p[1];
    bf16x8 o;
    o[0] = (bf16)a[0]; o[1] = (bf16)a[1]; o[2] = (bf16)a[2]; o[3] = (bf16)a[3];
    o[4] = (bf16)b[0]; o[5] = (bf16)b[1]; o[6] = (bf16)b[2]; o[7] = (bf16)b[3];
    *((bf16x8*)out + i) = o;
}

// ------- 256x256 / BK=64 / 8-wave / 32x32x16-MFMA / barrier-at-top blocks -------
// C[M,N] = act(A[M,K] * B[N,K]^T + bias1 (+bias2)). bf16 in, fp32 MFMA accum.
// Requires M%256==0, N%256==0, K%128==0.
//
// LDS (128 KiB dynamic): A = 2 bufs x 2 halves x [128 rows][64 cols] bf16,
// B same. Swizzle: LDS row r, 16B-granule slot s holds global granule
// s ^ (r&7); XOR applied on the global_load_lds SOURCE (dest stays linear),
// ds_reads XOR back. 0 bank conflicts (measured R2/R3; 32x32 pattern is
// uniform 8 lanes/granule-slot = minimal aliasing for b128).
//
// Block structure (R5, fixes R4's two races):
//   block p: { s_barrier ; MFMA8(slice read at block p-1) ;
//              RD6(slice for block p+1) ; STAGE? ; VMCNT? }
// RAW rule: every wave VMCNT(0)-drains its OWN stage DMAs BEFORE a barrier;
//   only after that barrier may any wave ds_read the staged region
//   (vmcnt is per-wave; R4 violated this by reading pre-barrier).
// WAR rule: reads at block p are lgkm-waited between bar(p+1) and bar(p+2),
//   so a stage may overwrite that region only at block >= p+3
//   (R4 staged at p+2 -> race; here: buf1 last read blk -1, staged blk 1,2;
//    buf0 last read blk 3, staged blk 5,6 -- both satisfied).
// VMCNT(0) at end of blk3 (drains Q(t1), read at blk4) and blk7 (drains
// P(t2), read at blk8). Outstanding at each drain = exactly the 8 loads
// issued 1-2 blocks earlier. Tail: t2 clamps to tile 0 (garbage into dead
// regions, never consumed); VMCNT(0) after the loop.
//
// 32x32x16 operand maps (hypothesis under test, schedule watertight):
// A: lane holds A[m = l&31][k = (l>>5)*8 + j] (contiguous octet, mirroring
// the pass-verified contiguous-octet 16x16x32 map); B symmetric on N^T rows.
// C/D (verified m74/m101): col = l&31, row = (r&3) + 8*(r>>2) + 4*(l>>5).
#define RD6(aset, bset, buf, ks) do { \
        aset[0] = *(const bf16x8*)(aAddr[ks] + (buf) * 16384 + 0 * 2048); \
        aset[1] = *(const bf16x8*)(aAddr[ks] + (buf) * 16384 + 1 * 2048); \
        aset[2] = *(const bf16x8*)(aAddr[ks] + (buf) * 16384 + 2 * 2048); \
        aset[3] = *(const bf16x8*)(aAddr[ks] + (buf) * 16384 + 3 * 2048); \
        bset[0] = *(const bf16x8*)(bAddr[ks] + (buf) * 16384 + 0 * 2048); \
        bset[1] = *(const bf16x8*)(bAddr[ks] + (buf) * 16384 + 1 * 2048); \
    } while (0)

#define STAGE(gsrc, lreg, h, kt) do { \
        const bf16* g_ = (gsrc) + (size_t)((h) * 128) * K + (size_t)(kt) * 64; \
        bf16* l_ = (lreg) + (h) * 8192 + wave * 1024; \
        __builtin_amdgcn_global_load_lds((gvoid*)g_,           (lvoid*)l_,         16, 0, 0); \
        __builtin_amdgcn_global_load_lds((gvoid*)(g_ + rowK8), (lvoid*)(l_ + 512), 16, 0, 0); \
    } while (0)

#define MFMA8(aset, bset) do { \
        __builtin_amdgcn_s_setprio(1); \
        _Pragma("unroll") \
        for (int mb_ = 0; mb_ < 4; ++mb_) \
            _Pragma("unroll") \
            for (int nb_ = 0; nb_ < 2; ++nb_) \
                acc[mb_][nb_] = __builtin_amdgcn_mfma_f32_32x32x16_bf16( \
                    aset[mb_], bset[nb_], acc[mb_][nb_], 0, 0, 0); \
        __builtin_amdgcn_s_setprio(0); \
    } while (0)

template<int RELU, int TWO_BIAS, int OUTF32>
__global__ __launch_bounds__(512, 2)
void gemm256(const bf16* __restrict__ A, const bf16* __restrict__ Bm,
             const float* __restrict__ bias1, const float* __restrict__ bias2,
             void* __restrict__ Cp, int M, int N, int K)
{
    extern __shared__ bf16 smem[];          // 131072 B
    bf16* As = smem;                        // 4 regions x 8192 elems
    bf16* Bs = smem + 32768;

    const int tid  = threadIdx.x;
    const int wave = tid >> 6;
    const int lane = tid & 63;
    const int wr   = wave >> 2;             // M half (0..1): wave owns 128x64
    const int wc   = wave & 3;              // N quarter (0..3)

    // XCD-aware bijective swizzle: nwg % 8 == 0 for all our grids (1024/512).
    const int nwg = gridDim.x * gridDim.y;
    int wg = blockIdx.y * gridDim.x + blockIdx.x;
    wg = (wg & 7) * (nwg >> 3) + (wg >> 3);
    const int bn = wg % gridDim.x;
    const int bm = wg / gridDim.x;

    // staging: lane -> row-in-chunk rc = lane>>3, swizzled granule (lane&7)^rc.
    const int rc  = lane >> 3;
    const int sgc = ((lane & 7) ^ rc) * 8;
    const bf16* aS0 = A  + (size_t)(bm * 256 + wave * 16 + rc) * K + sgc;
    const bf16* bS0 = Bm + (size_t)(bn * 256 + wave * 16 + rc) * K + sgc;
    const size_t rowK8 = (size_t)8 * K;

    // 32x32x16 fragment addressing: lane holds [m = l&31][k = (l>>5)*8 + j].
    // Granule of k-slice ks: gk = 2*ks + (l>>5); slot = gk ^ (row&7),
    // row&7 == lane&7 (all row-block offsets are multiples of 32).
    const int l31 = lane & 31;
    const int lh  = lane >> 5;
    const int fsw = lane & 7;

    const bf16* aAddr[4];
    const bf16* bAddr[4];
    #pragma unroll
    for (int ks = 0; ks < 4; ++ks) {
        const int slot = (2 * ks + lh) ^ fsw;
        aAddr[ks] = As + wr * 8192 + l31 * 64 + slot * 8;
        bAddr[ks] = Bs + (wc >> 1) * 8192 + (wc & 1) * 4096 + l31 * 64 + slot * 8;
    }

    bf16x8 afE[4], afO[4], bbE[2], bbO[2];
    f32x16 acc[4][2];
    #pragma unroll
    for (int i = 0; i < 4; ++i)
        #pragma unroll
        for (int j = 0; j < 2; ++j)
            acc[i][j] = (f32x16)(0.f);

    const int NT = K >> 6;                  // K-tiles (even)
    const int NI = NT >> 1;                 // iterations (2 tiles each)

    // prologue: stage P(t0) fully; drain own DMAs; barrier; pre-read P ks0.
    STAGE(aS0, As, 0, 0); STAGE(aS0, As, 1, 0);
    STAGE(bS0, Bs, 0, 0); STAGE(bS0, Bs, 1, 0);
    VMCNT(0);
    BARS();
    RD6(afE, bbE, 0, 0);

    for (int it = 0; it < NI; ++it) {
        const int t1 = 2 * it + 1;
        const int t2 = (2 * it + 2 < NT) ? 2 * it + 2 : 0;   // clamped tail

        // blk1: MFMA P ks0 | read P ks1 | stage Q.A(t1)
        BARS();
        MFMA8(afE, bbE);
        RD6(afO, bbO, 0, 1);
        STAGE(aS0, As + 16384, 0, t1);
        STAGE(aS0, As + 16384, 1, t1);
        // blk2: MFMA P ks1 | read P ks2 | stage Q.B(t1)
        BARS();
        MFMA8(afO, bbO);
        RD6(afE, bbE, 0, 2);
        STAGE(bS0, Bs + 16384, 0, t1);
        STAGE(bS0, Bs + 16384, 1, t1);
        // blk3: MFMA P ks2 | read P ks3 | drain own Q(t1) DMAs
        BARS();
        MFMA8(afE, bbE);
        RD6(afO, bbO, 0, 3);
        VMCNT(0);
        // blk4: MFMA P ks3 | read Q ks0 (fresh t1, safe: all drained + bar)
        BARS();
        MFMA8(afO, bbO);
        RD6(afE, bbE, 1, 0);
        // blk5: MFMA Q ks0 | read Q ks1 | stage P.A(t2) (buf0 last read blk3)
        BARS();
        MFMA8(afE, bbE);
        RD6(afO, bbO, 1, 1);
        STAGE(aS0, As, 0, t2);
        STAGE(aS0, As, 1, t2);
        // blk6: MFMA Q ks1 | read Q ks2 | stage P.B(t2)
        BARS();
        MFMA8(afO, bbO);
        RD6(afE, bbE, 1, 2);
        STAGE(bS0, Bs, 0, t2);
        STAGE(bS0, Bs, 1, t2);
        // blk7: MFMA Q ks2 | read Q ks3 | drain own P(t2) DMAs
        BARS();
        MFMA8(afE, bbE);
        RD6(afO, bbO, 1, 3);
        VMCNT(0);
        // blk8: MFMA Q ks3 | read P'(t2) ks0 (fresh, safe)
        BARS();
        MFMA8(afO, bbO);
        RD6(afE, bbE, 0, 0);
    }
    VMCNT(0);   // safety drain before LDS dealloc

    // ---- epilogue: 32x32 C/D layout col = l&31, row = (r&3)+8*(r>>2)+4*lh
    const int crow0 = bm * 256 + wr * 128 + 4 * lh;
    const int ccol0 = bn * 256 + wc * 64 + l31;

    float bv[2];
    #pragma unroll
    for (int nb = 0; nb < 2; ++nb) {
        bv[nb] = bias1[ccol0 + nb * 32];
        if (TWO_BIAS) bv[nb] += bias2[ccol0 + nb * 32];
    }

    #pragma unroll
    for (int mb = 0; mb < 4; ++mb) {
        #pragma unroll
        for (int rq = 0; rq < 4; ++rq) {
            #pragma unroll
            for (int rl = 0; rl < 4; ++rl) {
                const size_t row = (size_t)(crow0 + mb * 32 + rq * 8 + rl);
                #pragma unroll
                for (int nb = 0; nb < 2; ++nb) {
                    float v = acc[mb][nb][rq * 4 + rl] + bv[nb];
                    if (RELU) v = fmaxf(v, 0.0f);
                    if (OUTF32)
                        ((float*)Cp)[row * N + ccol0 + nb * 32] = v;
                    else
                        ((bf16*)Cp)[row * N + ccol0 + nb * 32] = (bf16)v;
                }
            }
        }
    }
}

static inline int cvt_blocks(size_t n) { return (int)((n / 8 + 255) / 256); }

extern "C" void kernel_launch(void* const* d_in, const int* in_sizes, int n_in,
                              void* d_out, int out_size, void* d_ws, size_t ws_size,
                              hipStream_t stream) {
    const float* x       = (const float*)d_in[0];  // [B,S,D_IN] fp32
    const float* W_init  = (const float*)d_in[1];  // [D_H, D_IN] fp32
    const float* b_init  = (const float*)d_in[2];  // [D_H] fp32
    const float* W_ih    = (const float*)d_in[3];  // [D_H, D_H] fp32
    const float* b_ih    = (const float*)d_in[4];  // [D_H] fp32
    const float* b_hh    = (const float*)d_in[5];  // [D_H] fp32
    const float* W_final = (const float*)d_in[6];  // [D_ACT, D_H] fp32
    const float* b_final = (const float*)d_in[7];  // [D_ACT] fp32
    float* out = (float*)d_out;                    // [B,S,D_ACT] fp32

    const int D_H   = in_sizes[2];               // 2048
    const int D_IN  = in_sizes[1] / D_H;         // 1024
    const int D_ACT = in_sizes[7];               // 1024
    const int M     = in_sizes[0] / D_IN;        // B*S = 32768

    const size_t nx  = (size_t)M * D_IN;
    const size_t nw1 = (size_t)D_H * D_IN;
    const size_t nw2 = (size_t)D_H * D_H;
    const size_t nw3 = (size_t)D_ACT * D_H;
    const size_t nh  = (size_t)M * D_H;

    // ws layout: [h: nh*2][a2: nh*2][w1b][w2b][w3b]; xb aliases a2's region
    // (x is dead before layer 2 writes a2 — same-stream ordering).
    char* ws  = (char*)d_ws;
    bf16* h   = (bf16*)ws;
    bf16* a2  = (bf16*)(ws + nh * 2);
    bf16* xb  = a2;                               // alias, see above
    bf16* w1b = (bf16*)(ws + nh * 4);
    bf16* w2b = w1b + nw1;
    bf16* w3b = w2b + nw2;

    // 128 KiB dynamic LDS opt-in (idempotent; harmless if already set)
    (void)hipFuncSetAttribute(reinterpret_cast<const void*>(&gemm256<1, 0, 0>),
                              hipFuncAttributeMaxDynamicSharedMemorySize, 131072);
    (void)hipFuncSetAttribute(reinterpret_cast<const void*>(&gemm256<1, 1, 0>),
                              hipFuncAttributeMaxDynamicSharedMemorySize, 131072);
    (void)hipFuncSetAttribute(reinterpret_cast<const void*>(&gemm256<0, 0, 1>),
                              hipFuncAttributeMaxDynamicSharedMemorySize, 131072);

    cvt_f32_bf16<<<cvt_blocks(nx),  256, 0, stream>>>(x,       xb,  (int)(nx  / 8));
    cvt_f32_bf16<<<cvt_blocks(nw1), 256, 0, stream>>>(W_init,  w1b, (int)(nw1 / 8));
    cvt_f32_bf16<<<cvt_blocks(nw2), 256, 0, stream>>>(W_ih,    w2b, (int)(nw2 / 8));
    cvt_f32_bf16<<<cvt_blocks(nw3), 256, 0, stream>>>(W_final, w3b, (int)(nw3 / 8));

    // layer 1: h = relu(x @ W_init^T + b_init)          [bf16 out]
    gemm256<1, 0, 0><<<dim3(D_H / 256, M / 256), 512, 131072, stream>>>(
        xb, w1b, b_init, nullptr, h, M, D_H, D_IN);

    // layer 2: a2 = relu(h @ W_ih^T + b_ih + b_hh)      [bf16 out]
    gemm256<1, 1, 0><<<dim3(D_H / 256, M / 256), 512, 131072, stream>>>(
        h, w2b, b_ih, b_hh, a2, M, D_H, D_H);

    // layer 3: out = a2 @ W_final^T + b_final           [fp32 out]
    gemm256<0, 0, 1><<<dim3(D_ACT / 256, M / 256), 512, 131072, stream>>>(
        a2, w3b, b_final, nullptr, out, M, D_ACT, D_H);
}